// Round 3
// baseline (9366.781 us; speedup 1.0000x reference)
//
#include <hip/hip_runtime.h>
#include <hip/hip_bf16.h>

#define H 128

// ---------------------------------------------------------------------------
// Fold per-relation linears into W1:
//   A_r[m][j] = sum_i Wl[r][i][m] * W1[j][r*H+i]      (mat = r in 0..2)
//   B[m][j]   = sum_r sum_i Wr[r][i][m] * W1[j][r*H+i] (mat = 3)
//   cvec[j]   = b1[j] + sum_r sum_i bl[r][i] * W1[j][r*H+i]
//   W2T[m][j] = W2[j][m]
// grid: 641 blocks x 128 threads
// ---------------------------------------------------------------------------
__global__ __launch_bounds__(128) void precompute_kernel(
    const float* __restrict__ Wl, const float* __restrict__ bl,
    const float* __restrict__ Wr, const float* __restrict__ W1,
    const float* __restrict__ b1, const float* __restrict__ W2,
    const float* __restrict__ b2,
    float* __restrict__ Am, float* __restrict__ W2T,
    float* __restrict__ cvec, float* __restrict__ b2f)
{
  int b = blockIdx.x;
  int j = threadIdx.x;
  if (b < 512) {
    int mat = b >> 7;      // 0..3
    int m   = b & 127;
    float s = 0.f;
    if (mat < 3) {
      int r = mat;
      for (int i = 0; i < H; i++)
        s += Wl[r*H*H + i*H + m] * W1[j*3*H + r*H + i];
    } else {
      for (int r = 0; r < 3; r++)
        for (int i = 0; i < H; i++)
          s += Wr[r*H*H + i*H + m] * W1[j*3*H + r*H + i];
    }
    Am[mat*H*H + m*H + j] = s;
  } else if (b == 512) {
    float s = b1[j];
    for (int r = 0; r < 3; r++)
      for (int i = 0; i < H; i++)
        s += bl[r*H + i] * W1[j*3*H + r*H + i];
    cvec[j] = s;
    b2f[j]  = b2[j];
  } else {
    int m = b - 513;       // 0..127
    W2T[m*H + j] = W2[j*H + m];
  }
}

// ---------------------------------------------------------------------------
// Edge aggregation for dst chunk [lo,hi): one wave per edge, lane handles 2
// f32 feats (coalesced 512B row gather), f32 atomic scatter into chunk agg.
// ---------------------------------------------------------------------------
__global__ __launch_bounds__(256) void edge_agg(
    const float* __restrict__ xsrc,
    const int* __restrict__ es, const int* __restrict__ ed,
    float* __restrict__ agg, int* __restrict__ cnt, int E, int lo, int hi)
{
  int wid  = (int)((blockIdx.x * 256u + threadIdx.x) >> 6);
  int lane = threadIdx.x & 63;
  int nw   = (int)((gridDim.x * 256u) >> 6);
  for (int e = wid; e < E; e += nw) {
    int d = ed[e];                      // wave-uniform (all lanes same e)
    if (d < lo || d >= hi) continue;
    int s = es[e];
    const float2* row = (const float2*)(xsrc + (size_t)s * H);
    float2 f = row[lane];
    float* a = agg + (size_t)(d - lo) * H + lane * 2;
    unsafeAtomicAdd(a,     f.x);
    unsafeAtomicAdd(a + 1, f.y);
    if (lane == 0) atomicAdd(cnt + (d - lo), 1);
  }
}

// ---------------------------------------------------------------------------
// init_pre: out[g][:] = cvec + xu[g] @ B     (f32)
// 64 nodes / 256-thread block; X staged in LDS (pad 129).
// ---------------------------------------------------------------------------
__global__ __launch_bounds__(256) void init_pre(
    const float* __restrict__ xu, const float* __restrict__ B,
    const float* __restrict__ cvec, float* __restrict__ out, int NU)
{
  __shared__ float xs[64][H + 1];
  int tid = threadIdx.x;
  int n   = tid >> 2;
  int j0  = (tid & 3) * 32;
  int g0  = blockIdx.x * 64;
  for (int idx = tid; idx < 64 * H; idx += 256) {
    int nn = idx >> 7, mm = idx & 127;
    int g  = g0 + nn;
    xs[nn][mm] = (g < NU) ? xu[(size_t)g * H + mm] : 0.f;
  }
  __syncthreads();
  float acc[32];
#pragma unroll
  for (int j = 0; j < 32; j++) acc[j] = cvec[j0 + j];
  for (int m = 0; m < H; m++) {
    float xm = xs[n][m];
    const float4* wr = (const float4*)(B + m * H + j0);
#pragma unroll
    for (int q = 0; q < 8; q++) {
      float4 w4 = wr[q];
      acc[q*4+0] += xm * w4.x; acc[q*4+1] += xm * w4.y;
      acc[q*4+2] += xm * w4.z; acc[q*4+3] += xm * w4.w;
    }
  }
  int g = g0 + n;
  if (g < NU) {
    float4* po = (float4*)(out + (size_t)g * H + j0);
#pragma unroll
    for (int q = 0; q < 8; q++)
      po[q] = make_float4(acc[4*q], acc[4*q+1], acc[4*q+2], acc[4*q+3]);
  }
}

// ---------------------------------------------------------------------------
// stage_add: out[g][:] += (agg[g-lo]/max(cnt,1)) @ W   for g in [lo,hi)
// ---------------------------------------------------------------------------
__global__ __launch_bounds__(256) void stage_add(
    const float* __restrict__ agg, const int* __restrict__ cnt,
    const float* __restrict__ W, float* __restrict__ out,
    int lo, int hi)
{
  __shared__ float xs[64][H + 1];
  int tid = threadIdx.x;
  int n   = tid >> 2;
  int j0  = (tid & 3) * 32;
  int g0  = lo + blockIdx.x * 64;
  for (int idx = tid; idx < 64 * H; idx += 256) {
    int nn = idx >> 7, mm = idx & 127;
    int g  = g0 + nn;
    float v = 0.f;
    if (g < hi) {
      int cc = cnt[g - lo];
      v = agg[(size_t)(g - lo) * H + mm] / (float)(cc > 0 ? cc : 1);
    }
    xs[nn][mm] = v;
  }
  __syncthreads();
  float acc[32];
#pragma unroll
  for (int j = 0; j < 32; j++) acc[j] = 0.f;
  for (int m = 0; m < H; m++) {
    float xm = xs[n][m];
    const float4* wr = (const float4*)(W + m * H + j0);
#pragma unroll
    for (int q = 0; q < 8; q++) {
      float4 w4 = wr[q];
      acc[q*4+0] += xm * w4.x; acc[q*4+1] += xm * w4.y;
      acc[q*4+2] += xm * w4.z; acc[q*4+3] += xm * w4.w;
    }
  }
  int g = g0 + n;
  if (g < hi) {
    float4* po = (float4*)(out + (size_t)g * H + j0);
#pragma unroll
    for (int q = 0; q < 8; q++) {
      float4 cur = po[q];
      po[q] = make_float4(cur.x + acc[4*q],   cur.y + acc[4*q+1],
                          cur.z + acc[4*q+2], cur.w + acc[4*q+3]);
    }
  }
}

// ---------------------------------------------------------------------------
// final_mlp: out[g][:] = relu(out[g][:]) @ W2T + b2   (in place, block owns rows)
// ---------------------------------------------------------------------------
__global__ __launch_bounds__(256) void final_mlp(
    const float* __restrict__ W2T, const float* __restrict__ b2f,
    float* __restrict__ out, int NU)
{
  __shared__ float xs[64][H + 1];
  int tid = threadIdx.x;
  int n   = tid >> 2;
  int j0  = (tid & 3) * 32;
  int g0  = blockIdx.x * 64;
  for (int idx = tid; idx < 64 * H; idx += 256) {
    int nn = idx >> 7, mm = idx & 127;
    int g  = g0 + nn;
    float v = 0.f;
    if (g < NU) {
      v = out[(size_t)g * H + mm];
      v = v > 0.f ? v : 0.f;
    }
    xs[nn][mm] = v;
  }
  __syncthreads();
  float o[32];
#pragma unroll
  for (int j = 0; j < 32; j++) o[j] = b2f[j0 + j];
  for (int m = 0; m < H; m++) {
    float hm = xs[n][m];
    const float4* wr = (const float4*)(W2T + m * H + j0);
#pragma unroll
    for (int q = 0; q < 8; q++) {
      float4 w4 = wr[q];
      o[q*4+0] += hm * w4.x; o[q*4+1] += hm * w4.y;
      o[q*4+2] += hm * w4.z; o[q*4+3] += hm * w4.w;
    }
  }
  int g = g0 + n;
  if (g < NU) {
    float4* po = (float4*)(out + (size_t)g * H + j0);
#pragma unroll
    for (int q = 0; q < 8; q++)
      po[q] = make_float4(o[4*q], o[4*q+1], o[4*q+2], o[4*q+3]);
  }
}

extern "C" void kernel_launch(void* const* d_in, const int* in_sizes, int n_in,
                              void* d_out, int out_size, void* d_ws, size_t ws_size,
                              hipStream_t stream) {
  (void)n_in; (void)out_size;
  const float* xu = (const float*)d_in[0];
  const float* xt = (const float*)d_in[1];
  const float* xd = (const float*)d_in[2];
  const int* ess[3] = { (const int*)d_in[3], (const int*)d_in[5], (const int*)d_in[7] };
  const int* eds[3] = { (const int*)d_in[4], (const int*)d_in[6], (const int*)d_in[8] };
  const float* Wl = (const float*)d_in[9];
  const float* bl = (const float*)d_in[10];
  const float* Wr = (const float*)d_in[11];
  const float* W1 = (const float*)d_in[12];
  const float* b1 = (const float*)d_in[13];
  const float* W2 = (const float*)d_in[14];
  const float* b2 = (const float*)d_in[15];
  const float* srcs[3] = { xt, xd, xu };
  int Es[3] = { in_sizes[3], in_sizes[5], in_sizes[7] };

  const int NU = in_sizes[0] / H;     // 200000
  float* out = (float*)d_out;

  // ---- workspace layout (small, adaptive) ----
  char* ws = (char*)d_ws;
  float* Am   = (float*)(ws);                        // 4*H*H f32 = 262144 B
  float* W2T  = (float*)(ws + 262144);               // H*H f32   =  65536 B
  float* cvec = (float*)(ws + 262144 + 65536);       // 128 f32   =    512 B
  float* b2f  = (float*)(ws + 262144 + 65536 + 512); // 128 f32   =    512 B
  size_t agg_off = 262144 + 65536 + 512 + 512;       // 328704, 4-aligned

  // per chunk-node: H f32 agg + 1 int cnt = 516 B
  long cap = ((long)ws_size - (long)agg_off - 256) / 516L;
  int NC;
  if (cap >= (long)NU) NC = NU;
  else {
    NC = (int)cap & ~63;
    if (NC < 64) NC = 64;
  }
  int nchunks = (NU + NC - 1) / NC;
  float* agg = (float*)(ws + agg_off);
  int*   cnt = (int*)(ws + agg_off + (size_t)NC * H * sizeof(float));

  precompute_kernel<<<641, 128, 0, stream>>>(Wl, bl, Wr, W1, b1, W2, b2,
                                             Am, W2T, cvec, b2f);
  init_pre<<<(NU + 63) / 64, 256, 0, stream>>>(xu, Am + 3*H*H, cvec, out, NU);

  for (int c = 0; c < nchunks; c++) {
    int lo = c * NC;
    int hi = lo + NC < NU ? lo + NC : NU;
    for (int r = 0; r < 3; r++) {
      hipMemsetAsync(agg, 0, (size_t)NC * 516, stream);   // agg + cnt contiguous
      edge_agg<<<4096, 256, 0, stream>>>(srcs[r], ess[r], eds[r],
                                         agg, cnt, Es[r], lo, hi);
      stage_add<<<(hi - lo + 63) / 64, 256, 0, stream>>>(
          agg, cnt, Am + r*H*H, out, lo, hi);
    }
  }
  final_mlp<<<(NU + 63) / 64, 256, 0, stream>>>(W2T, b2f, out, NU);
}

// Round 4
// 1499.611 us; speedup vs baseline: 6.2461x; 6.2461x over previous
//
#include <hip/hip_runtime.h>

#define H 128

// ---------------------------------------------------------------------------
// Fold per-relation linears into W1:
//   A_r[m][j] = sum_i Wl[r][i][m] * W1[j][r*H+i]      (mat = r in 0..2)
//   B[m][j]   = sum_r sum_i Wr[r][i][m] * W1[j][r*H+i] (mat = 3)
//   cvec[j]   = b1[j] + sum_r sum_i bl[r][i] * W1[j][r*H+i]
//   W2T[m][j] = W2[j][m]
// ---------------------------------------------------------------------------
__global__ __launch_bounds__(128) void precompute_kernel(
    const float* __restrict__ Wl, const float* __restrict__ bl,
    const float* __restrict__ Wr, const float* __restrict__ W1,
    const float* __restrict__ b1, const float* __restrict__ W2,
    const float* __restrict__ b2,
    float* __restrict__ Am, float* __restrict__ W2T,
    float* __restrict__ cvec, float* __restrict__ b2f)
{
  int b = blockIdx.x;
  int j = threadIdx.x;
  if (b < 512) {
    int mat = b >> 7;      // 0..3
    int m   = b & 127;
    float s = 0.f;
    if (mat < 3) {
      int r = mat;
      for (int i = 0; i < H; i++)
        s += Wl[r*H*H + i*H + m] * W1[j*3*H + r*H + i];
    } else {
      for (int r = 0; r < 3; r++)
        for (int i = 0; i < H; i++)
          s += Wr[r*H*H + i*H + m] * W1[j*3*H + r*H + i];
    }
    Am[mat*H*H + m*H + j] = s;
  } else if (b == 512) {
    float s = b1[j];
    for (int r = 0; r < 3; r++)
      for (int i = 0; i < H; i++)
        s += bl[r*H + i] * W1[j*3*H + r*H + i];
    cvec[j] = s;
    b2f[j]  = b2[j];
  } else {
    int m = b - 513;       // 0..127
    W2T[m*H + j] = W2[j*H + m];
  }
}

// ---------------------------- CSR build ------------------------------------
__global__ __launch_bounds__(256) void k_hist(const int* __restrict__ ed,
                                              int* __restrict__ cnt, int E) {
  int i = blockIdx.x * 256 + threadIdx.x;
  if (i < E) atomicAdd(&cnt[ed[i]], 1);
}

__global__ __launch_bounds__(256) void k_scan1(const int* __restrict__ deg,
                                               int* __restrict__ off1,
                                               int* __restrict__ bsum, int n) {
  __shared__ int tmp[256];
  int i = blockIdx.x * 256 + threadIdx.x;
  int v = (i < n) ? deg[i] : 0;
  tmp[threadIdx.x] = v;
  __syncthreads();
  for (int s = 1; s < 256; s <<= 1) {
    int t = (threadIdx.x >= (unsigned)s) ? tmp[threadIdx.x - s] : 0;
    __syncthreads();
    tmp[threadIdx.x] += t;
    __syncthreads();
  }
  if (i < n) off1[i + 1] = tmp[threadIdx.x];     // local inclusive, block offset pending
  if (threadIdx.x == 255) bsum[blockIdx.x] = tmp[255];
}

__global__ __launch_bounds__(1024) void k_scan2(int* __restrict__ bsum, int nb) {
  __shared__ int tmp[1024];
  __shared__ int carry;
  if (threadIdx.x == 0) carry = 0;
  __syncthreads();
  for (int base = 0; base < nb; base += 1024) {
    int i = base + threadIdx.x;
    int v = (i < nb) ? bsum[i] : 0;
    tmp[threadIdx.x] = v;
    __syncthreads();
    for (int s = 1; s < 1024; s <<= 1) {
      int t = (threadIdx.x >= (unsigned)s) ? tmp[threadIdx.x - s] : 0;
      __syncthreads();
      tmp[threadIdx.x] += t;
      __syncthreads();
    }
    if (i < nb) bsum[i] = carry + tmp[threadIdx.x] - v;   // exclusive
    __syncthreads();
    if (threadIdx.x == 0) carry += tmp[1023];
    __syncthreads();
  }
}

__global__ __launch_bounds__(256) void k_scan3(int* __restrict__ off,
                                               const int* __restrict__ bsum, int n) {
  int i = blockIdx.x * 256 + threadIdx.x;
  if (i < n) off[i + 1] += bsum[blockIdx.x];
  if (blockIdx.x == 0 && threadIdx.x == 0) off[0] = 0;
}

__global__ __launch_bounds__(256) void k_copy(const int* __restrict__ off,
                                              int* __restrict__ cur, int n) {
  int i = blockIdx.x * 256 + threadIdx.x;
  if (i < n) cur[i] = off[i];
}

__global__ __launch_bounds__(256) void k_scatter(const int* __restrict__ es,
                                                 const int* __restrict__ ed,
                                                 int* __restrict__ cur,
                                                 int* __restrict__ nbr, int E) {
  int i = blockIdx.x * 256 + threadIdx.x;
  if (i < E) {
    int d = ed[i];
    int pos = atomicAdd(&cur[d], 1);
    nbr[pos] = es[i];
  }
}

// ---------------------------- fused node kernel ----------------------------
// 64 nodes / 256-thread block. Thread t: c = t&7 (16-col group j0=c*16),
// nA = t>>3 (0..31) -> handles nodes nA and nA+32.
// xs[64][130] f32 x-tile; wb: swizzled weight chunk, per-c stride 516 dwords
// (bank quad 4c -> conflict-free ds_read_b128 with 8-way broadcast).
// ---------------------------------------------------------------------------
__device__ __forceinline__ void mm_accum(const float* __restrict__ W,
                                         float (*xs)[130], float* wb,
                                         float2* acc0, float2* acc1,
                                         int tid, int nA, int c)
{
  for (int mc = 0; mc < 4; mc++) {
    __syncthreads();                       // wb safe to overwrite
    {
      int m = tid >> 3;                    // 0..31
      const float4* s4 = (const float4*)(W + (size_t)(mc * 32 + m) * H + c * 16);
      float4* dd = (float4*)(wb + c * 516 + m * 16);
      dd[0] = s4[0]; dd[1] = s4[1]; dd[2] = s4[2]; dd[3] = s4[3];
    }
    __syncthreads();
    const float* xr0 = &xs[nA][mc * 32];
    const float* xr1 = &xs[nA + 32][mc * 32];
    const float4* wq = (const float4*)(wb + c * 516);
#pragma unroll 4
    for (int m = 0; m < 32; m++) {
      float xm0 = xr0[m], xm1 = xr1[m];
      const float4* w4 = wq + m * 4;
#pragma unroll
      for (int q = 0; q < 4; q++) {
        float4 w = w4[q];
        acc0[2*q].x   += xm0 * w.x; acc0[2*q].y   += xm0 * w.y;
        acc0[2*q+1].x += xm0 * w.z; acc0[2*q+1].y += xm0 * w.w;
        acc1[2*q].x   += xm1 * w.x; acc1[2*q].y   += xm1 * w.y;
        acc1[2*q+1].x += xm1 * w.z; acc1[2*q+1].y += xm1 * w.w;
      }
    }
  }
}

__global__ __launch_bounds__(256) void k_fused(
    const float* __restrict__ xu, const float* __restrict__ xt,
    const float* __restrict__ xd,
    const int* __restrict__ off0, const int* __restrict__ nbr0,
    const int* __restrict__ off1, const int* __restrict__ nbr1,
    const int* __restrict__ off2, const int* __restrict__ nbr2,
    const float* __restrict__ Am, const float* __restrict__ W2T,
    const float* __restrict__ cvec, const float* __restrict__ b2f,
    float* __restrict__ out, int NU)
{
  __shared__ float xs[64][130];
  __shared__ float wb[8 * 516];
  int tid = threadIdx.x;
  int wv = tid >> 6, ln = tid & 63;
  int c = tid & 7, j0 = c * 16, nA = tid >> 3;
  int g0 = blockIdx.x * 64;

  float2 acc0[8], acc1[8];
#pragma unroll
  for (int q = 0; q < 8; q++) {
    acc0[q] = make_float2(cvec[j0 + 2*q], cvec[j0 + 2*q + 1]);
    acc1[q] = acc0[q];
  }

  for (int s = 0; s < 4; s++) {
    __syncthreads();                       // xs safe to overwrite
    const float* xsrc = (s == 0) ? xt : (s == 1) ? xd : xu;
    const int* offp = (s == 0) ? off0 : (s == 1) ? off1 : off2;
    const int* nbrp = (s == 0) ? nbr0 : (s == 1) ? nbr1 : nbr2;
    for (int k = 0; k < 16; k++) {
      int n = wv * 16 + k;
      int g = g0 + n;
      float vx = 0.f, vy = 0.f;
      if (g < NU) {
        if (s == 3) {
          float2 t = ((const float2*)(xu + (size_t)g * H))[ln];
          vx = t.x; vy = t.y;
        } else {
          int beg = offp[g], end = offp[g + 1];
          for (int e = beg; e < end; e++) {
            int srow = nbrp[e];
            float2 t = ((const float2*)(xsrc + (size_t)srow * H))[ln];
            vx += t.x; vy += t.y;
          }
          float inv = 1.f / (float)((end - beg) > 0 ? (end - beg) : 1);
          vx *= inv; vy *= inv;
        }
      }
      *((float2*)&xs[n][2 * ln]) = make_float2(vx, vy);
    }
    __syncthreads();
    mm_accum(Am + (size_t)s * H * H, xs, wb, acc0, acc1, tid, nA, c);
  }

  __syncthreads();
  // h = relu(pre) -> xs
#pragma unroll
  for (int q = 0; q < 8; q++) {
    float2 a = acc0[q], b = acc1[q];
    xs[nA][j0 + 2*q]       = a.x > 0.f ? a.x : 0.f;
    xs[nA][j0 + 2*q + 1]   = a.y > 0.f ? a.y : 0.f;
    xs[nA+32][j0 + 2*q]     = b.x > 0.f ? b.x : 0.f;
    xs[nA+32][j0 + 2*q + 1] = b.y > 0.f ? b.y : 0.f;
  }
  __syncthreads();
#pragma unroll
  for (int q = 0; q < 8; q++) {
    acc0[q] = make_float2(b2f[j0 + 2*q], b2f[j0 + 2*q + 1]);
    acc1[q] = acc0[q];
  }
  mm_accum(W2T, xs, wb, acc0, acc1, tid, nA, c);

  int gA = g0 + nA, gB = gA + 32;
  if (gA < NU) {
    float4* po = (float4*)(out + (size_t)gA * H + j0);
#pragma unroll
    for (int q = 0; q < 4; q++)
      po[q] = make_float4(acc0[2*q].x, acc0[2*q].y, acc0[2*q+1].x, acc0[2*q+1].y);
  }
  if (gB < NU) {
    float4* po = (float4*)(out + (size_t)gB * H + j0);
#pragma unroll
    for (int q = 0; q < 4; q++)
      po[q] = make_float4(acc1[2*q].x, acc1[2*q].y, acc1[2*q+1].x, acc1[2*q+1].y);
  }
}

extern "C" void kernel_launch(void* const* d_in, const int* in_sizes, int n_in,
                              void* d_out, int out_size, void* d_ws, size_t ws_size,
                              hipStream_t stream) {
  (void)n_in; (void)out_size; (void)ws_size;
  const float* xu = (const float*)d_in[0];
  const float* xt = (const float*)d_in[1];
  const float* xd = (const float*)d_in[2];
  const int* ess[3] = { (const int*)d_in[3], (const int*)d_in[5], (const int*)d_in[7] };
  const int* eds[3] = { (const int*)d_in[4], (const int*)d_in[6], (const int*)d_in[8] };
  const float* Wl = (const float*)d_in[9];
  const float* bl = (const float*)d_in[10];
  const float* Wr = (const float*)d_in[11];
  const float* W1 = (const float*)d_in[12];
  const float* b1 = (const float*)d_in[13];
  const float* W2 = (const float*)d_in[14];
  const float* b2 = (const float*)d_in[15];
  int Es[3] = { in_sizes[3], in_sizes[5], in_sizes[7] };

  const int NU = in_sizes[0] / H;          // 200000
  const int NB = (NU + 255) / 256;         // scan blocks
  float* out = (float*)d_out;

  // ---- workspace layout ----
  char* p = (char*)d_ws;
  size_t pos = 0;
  auto take = [&](size_t bytes) -> char* {
    char* r = p + pos;
    pos = (pos + bytes + 255) & ~(size_t)255;
    return r;
  };
  float* Am   = (float*)take((size_t)4 * H * H * sizeof(float));
  float* W2T  = (float*)take((size_t)H * H * sizeof(float));
  float* cvec = (float*)take(512);
  float* b2f  = (float*)take(512);
  int* curA   = (int*)take((size_t)3 * NU * sizeof(int));   // 3 contiguous cursor/deg arrays
  int* offr[3]; int* bsum[3]; int* nbr[3];
  for (int r = 0; r < 3; r++) offr[r] = (int*)take((size_t)(NU + 1) * sizeof(int));
  for (int r = 0; r < 3; r++) bsum[r] = (int*)take((size_t)(NB + 1) * sizeof(int));
  for (int r = 0; r < 3; r++) nbr[r]  = (int*)take((size_t)Es[r] * sizeof(int));

  int* cur[3] = { curA, curA + NU, curA + 2 * NU };

  precompute_kernel<<<641, 128, 0, stream>>>(Wl, bl, Wr, W1, b1, W2, b2,
                                             Am, W2T, cvec, b2f);
  hipMemsetAsync(curA, 0, (size_t)3 * NU * sizeof(int), stream);

  for (int r = 0; r < 3; r++)
    k_hist<<<(Es[r] + 255) / 256, 256, 0, stream>>>(eds[r], cur[r], Es[r]);
  for (int r = 0; r < 3; r++)
    k_scan1<<<NB, 256, 0, stream>>>(cur[r], offr[r], bsum[r], NU);
  for (int r = 0; r < 3; r++)
    k_scan2<<<1, 1024, 0, stream>>>(bsum[r], NB);
  for (int r = 0; r < 3; r++)
    k_scan3<<<NB, 256, 0, stream>>>(offr[r], bsum[r], NU);
  for (int r = 0; r < 3; r++)
    k_copy<<<NB, 256, 0, stream>>>(offr[r], cur[r], NU);
  for (int r = 0; r < 3; r++)
    k_scatter<<<(Es[r] + 255) / 256, 256, 0, stream>>>(ess[r], eds[r], cur[r],
                                                       nbr[r], Es[r]);

  k_fused<<<(NU + 63) / 64, 256, 0, stream>>>(
      xu, xt, xd,
      offr[0], nbr[0], offr[1], nbr[1], offr[2], nbr[2],
      Am, W2T, cvec, b2f, out, NU);
}